// Round 4
// baseline (249.142 us; speedup 1.0000x reference)
//
#include <hip/hip_runtime.h>

#define H 512
#define W 512
#define K 5
#define PAD 2
#define TROWS 8                       // output rows per block
#define IROWS (TROWS + K - 1)         // 12 staged input rows
#define XPT 4                         // output cols per thread (one float4)
#define NCHUNK (IROWS * W * 4 / 16)   // 1536 16-byte chunks per tile
#define CPT (NCHUNK / 256)            // 6 chunks staged per thread

typedef float vf4 __attribute__((ext_vector_type(4)));

// Rounds 1-3 proved the bottleneck is unhidden VMEM latency and that the
// compiler defeats every register-level software pipeline (it re-sinks
// loads to point-of-use; VGPR=52 in round 2 was the tell). Fix: stage each
// block's input tile into LDS with __builtin_amdgcn_global_load_lds -- an
// async DMA with NO register destination, so it structurally cannot be
// re-sunk. One vmcnt(0) drain at the barrier per block; compute then runs
// on ~12-cycle ds_read_b128. Latency hiding becomes TLP: 24 KB LDS -> 6
// blocks/CU; while one block drains its stage, five compute. Full-width
// rows make staging affine (1536 aligned 16B chunks, 6/thread) and remove
// x-halo global loads; window edges are clamped+masked LDS reads with the
// exact v[]-mask values and FMA order of all passing rounds.
__global__ __launch_bounds__(256, 6) void conv5x5_kernel(
    const float* __restrict__ X, const float* __restrict__ ker,
    float* __restrict__ out)
{
    __shared__ float tile[IROWS][W];          // 24 KB

    const int tx  = threadIdx.x;              // 0..255
    const int y0  = blockIdx.x * TROWS;       // 0,8,...,504
    const int img = blockIdx.y;               // 0..127

    const float* Xp = X   + (size_t)img * H * W;
    float*       Op = out + (size_t)img * H * W;

    // ---- async stage: 12 full-width rows -> LDS (no VGPR destination) ----
    #pragma unroll
    for (int k = 0; k < CPT; ++k) {
        const int c   = tx + 256 * k;         // chunk id 0..1535
        const int rr  = c >> 7;               // staged row 0..11 (128 chunks/row)
        const int c16 = c & 127;              // 16B chunk within row
        int yr = y0 - PAD + rr;
        yr = yr < 0 ? 0 : (yr > H - 1 ? H - 1 : yr);   // clamped; masked at use
        const float* src = Xp + (size_t)yr * W + c16 * 4;
        __builtin_amdgcn_global_load_lds(
            (const __attribute__((address_space(1))) void*)src,
            (__attribute__((address_space(3))) void*)&tile[rr][c16 * 4],
            16, 0, 0);
    }

    // kernel coeffs: uniform address -> scalar loads into SGPRs (overlaps DMA)
    float kk[K][K];
    #pragma unroll
    for (int i = 0; i < K; ++i)
        #pragma unroll
        for (int j = 0; j < K; ++j)
            kk[i][j] = ker[i * K + j];

    __syncthreads();                          // vmcnt(0) drain + barrier

    // ---- compute from LDS ----
    const int q  = tx & 127;                  // vf4 column 0..127
    const int ty = tx >> 7;                   // 0..1 (4 output rows each)
    const int qL = (q == 0)   ? 0 : q - 1;    // clamped: always in-bounds
    const int qR = (q == 127) ? q : q + 1;
    const float mLo = (q == 0)   ? 0.f : 1.f; // zero v[0],v[1] at left edge
    const float mHi = (q == 127) ? 0.f : 1.f; // zero v[6],v[7] at right edge
    const int rbase = ty * 4;

    float acc[4][XPT];
    #pragma unroll
    for (int o = 0; o < 4; ++o)
        #pragma unroll
        for (int j = 0; j < XPT; ++j)
            acc[o][j] = 0.f;

    #pragma unroll
    for (int r = 0; r < 8; ++r) {             // 8 input rows per thread
        const int lr = rbase + r;             // LDS row 0..11
        const int yr = y0 - PAD + lr;         // global input row
        const float mR = (yr >= 0 && yr < H) ? 1.f : 0.f;
        const vf4* rp = (const vf4*)&tile[lr][0];
        const vf4 Lv = rp[qL];
        const vf4 Mv = rp[q];
        const vf4 Rv = rp[qR];
        const float mA = mLo * mR;
        const float mC = mHi * mR;
        // window v[0..7] = input cols q*4-2 .. q*4+5 (same values as before)
        float v[8];
        v[0] = Lv.z * mA;  v[1] = Lv.w * mA;
        v[2] = Mv.x * mR;  v[3] = Mv.y * mR;
        v[4] = Mv.z * mR;  v[5] = Mv.w * mR;
        v[6] = Rv.x * mC;  v[7] = Rv.y * mC;

        // per output row: kr = 0..4, c = 0..4 -- identical order/numerics
        #pragma unroll
        for (int o = 0; o < 4; ++o) {
            const int kr = r - o;
            if (kr >= 0 && kr < K) {
                #pragma unroll
                for (int c = 0; c < K; ++c)
                    #pragma unroll
                    for (int j = 0; j < XPT; ++j)
                        acc[o][j] = fmaf(v[j + c], kk[kr][c], acc[o][j]);
            }
        }
    }

    #pragma unroll
    for (int o = 0; o < 4; ++o) {
        vf4 st = {acc[o][0], acc[o][1], acc[o][2], acc[o][3]};
        __builtin_nontemporal_store(
            st, (vf4*)(Op + (size_t)(y0 + rbase + o) * W + q * XPT));
    }
}

extern "C" void kernel_launch(void* const* d_in, const int* in_sizes, int n_in,
                              void* d_out, int out_size, void* d_ws, size_t ws_size,
                              hipStream_t stream) {
    const float* X   = (const float*)d_in[0];
    const float* ker = (const float*)d_in[1];
    float* out = (float*)d_out;

    dim3 block(256, 1, 1);
    dim3 grid(H / TROWS, 4 * 32, 1);          // (64, 128): y-tile x image
    hipLaunchKernelGGL(conv5x5_kernel, grid, block, 0, stream, X, ker, out);
}